// Round 11
// baseline (12.328 us; speedup 1.0000x reference)
//
#include <hip/hip_runtime.h>

// DichotomicSolver: per-row root-find of Dm(m)=mean(sigmoid(30(m-x)))-0.5.
// R11: software-pipeline 2 rows per wave. R8/R9/R10 all pinned at ~11 us
// because all 4096 waves loaded simultaneously (one generation): a ~5.3 us
// pure-memory drain (compute idle; n50 needs the full row) followed by a
// pure-compute phase. Now each wave issues row-A loads THEN row-B loads,
// solves A while B is in flight (FIFO vmcnt(8)), then solves B -> compute
// hides inside the drain; tail = one row's solve.
// Per-row math identical to R8/R10 (absmax 0.75 expected):
//   n50 count -> inverse-CDF c0; band |x-c0|<=1.7 (below-band sigmoid ==
//   1.0f bit-exact, 30*(1.7-1.1)=18; above-band <3e-5 counts); 4 bracketed
//   Newton iters in [c0-1.1, c0+1.1]; ballot-bisection fallback (never taken
//   for this input). No __syncthreads anywhere; per-wave LDS band slices.

constexpr int   S_DIM = 2048;
constexpr int   EPL   = S_DIM / 64;            // 32 elements per lane
constexpr float KL2E  = 43.280851308343876f;   // 30 * log2(e)
constexpr int   BANDC = 128;                   // band capacity (mean ~70, max ~102)
constexpr float BHW   = 1.7f;                  // band half-width
constexpr float MCL   = 1.1f;                  // Newton bracket half-width
constexpr int   NNEWT = 4;
constexpr int   RPW   = 2;                     // rows per wave (pipeline depth)

template<int CTRL, int RMASK>
__device__ __forceinline__ int dpp_add_i(int v) {
    return v + __builtin_amdgcn_update_dpp(0, v, CTRL, RMASK, 0xF, true);
}

// wave64 inclusive +scan (gfx9 row_shr/row_bcast sequence)
__device__ __forceinline__ int wave_iscan_incl(int v) {
    v = dpp_add_i<0x111, 0xF>(v);
    v = dpp_add_i<0x112, 0xF>(v);
    v = dpp_add_i<0x114, 0xF>(v);
    v = dpp_add_i<0x118, 0xF>(v);
    v = dpp_add_i<0x142, 0xA>(v);
    v = dpp_add_i<0x143, 0xC>(v);
    return v;
}

template<int CTRL>
__device__ __forceinline__ float dpp_add_f(float v) {
    int sh = __builtin_amdgcn_update_dpp(0, __float_as_int(v), CTRL, 0xF, 0xF, true);
    return v + __int_as_float(sh);
}

// full wave64 sum broadcast (pure VALU DPP + readlane)
__device__ __forceinline__ float wave_reduce_bcast(float v) {
    v = dpp_add_f<0x111>(v);
    v = dpp_add_f<0x112>(v);
    v = dpp_add_f<0x114>(v);
    v = dpp_add_f<0x118>(v);
    v = dpp_add_f<0x142>(v);
    v = dpp_add_f<0x143>(v);
    return __int_as_float(__builtin_amdgcn_readlane(__float_as_int(v), 63));
}

__device__ __forceinline__ float sig(float xv, float m) {
    float e = __builtin_amdgcn_exp2f((xv - m) * KL2E);
    return __builtin_amdgcn_rcpf(1.0f + e);
}

// Solve one row held as 8 float4/lane. bandp = this wave's private LDS slice.
__device__ __forceinline__ float solve_row(const float4 (&v4)[EPL / 4],
                                           float* bandp, int lane) {
    float xs[EPL];
    int c50 = 0;
    #pragma unroll
    for (int j = 0; j < EPL / 4; ++j) {
        xs[4*j+0] = v4[j].x; xs[4*j+1] = v4[j].y;
        xs[4*j+2] = v4[j].z; xs[4*j+3] = v4[j].w;
        c50 += (v4[j].x < 50.0f) ? 1 : 0;
        c50 += (v4[j].y < 50.0f) ? 1 : 0;
        c50 += (v4[j].z < 50.0f) ? 1 : 0;
        c50 += (v4[j].w < 50.0f) ? 1 : 0;
    }

    // inverse-CDF estimate from n50 (one int DPP reduce)
    const int n50 = __builtin_amdgcn_readlane(wave_iscan_incl(c50), 63);
    float c0 = 50.0f + (float)(S_DIM / 2 - n50) * (100.0f / (float)S_DIM);
    c0 = fminf(100.0f, fmaxf(0.0f, c0));

    // band membership + exact ranks via ONE packed int DPP scan
    const float blo = c0 - BHW, bhi = c0 + BHW;
    int below_l = 0, nb_l = 0;
    #pragma unroll
    for (int j = 0; j < EPL; ++j) {
        below_l += (xs[j] < blo) ? 1 : 0;
        nb_l    += (xs[j] >= blo && xs[j] <= bhi) ? 1 : 0;
    }
    const int packed = (below_l << 16) | nb_l;
    const int pincl  = wave_iscan_incl(packed);
    const int ptot   = __builtin_amdgcn_readlane(pincl, 63);
    const int belowN = ptot >> 16;
    const int nbtot  = ptot & 0xffff;

    const bool ok = (nbtot <= BANDC) && (belowN < S_DIM / 2)
                 && (belowN + nbtot > S_DIM / 2);        // wave-uniform
    if (ok) {
        // scatter band to private LDS slice at exact deterministic ranks
        int k = (pincl - packed) & 0xffff;
        #pragma unroll
        for (int j = 0; j < EPL; ++j) {
            if (xs[j] >= blo && xs[j] <= bhi) bandp[k++] = xs[j];
        }
        // hoist into 2 regs/lane (in-wave DS ordering: no barrier needed)
        const bool  v0 = lane < nbtot, v1 = lane + 64 < nbtot;
        const float a0 = bandp[lane];
        const float a1 = bandp[lane + 64];
        const float below = (float)belowN;

        float Lb = c0 - MCL, Rb = c0 + MCL, m = c0;
        #pragma unroll
        for (int t = 0; t < NNEWT; ++t) {
            const float r0 = sig(a0, m), r1 = sig(a1, m);
            const float S = (v0 ? r0 : 0.0f) + (v1 ? r1 : 0.0f);
            const float T = (v0 ? r0 * (1.0f - r0) : 0.0f)
                          + (v1 ? r1 * (1.0f - r1) : 0.0f);
            const float Stot = wave_reduce_bcast(S) + below;
            const float Ttot = wave_reduce_bcast(T);
            const float D  = Stot * (1.0f / (float)S_DIM) - 0.5f;
            const float Dp = Ttot * (30.0f / (float)S_DIM);
            if (D > 0.0f) Rb = m; else Lb = m;
            float mn = m - D * __builtin_amdgcn_rcpf(Dp + 1e-20f);
            if (!(mn > Lb && mn < Rb)) mn = (Lb + Rb) * 0.5f;
            m = mn;
        }
        return m;
    }

    // Fallback (never taken for this input): ballot bisection + 3 clamped
    // full-width Newton, registers only.
    float lo = 0.0f, hi = 100.0f;
    #pragma unroll 1
    for (int t = 0; t < 16; ++t) {
        const float c = (lo + hi) * 0.5f;
        int cnt = 0;
        #pragma unroll
        for (int j = 0; j < EPL; ++j)
            cnt += __popcll(__ballot(xs[j] < c));
        if (cnt >= S_DIM / 2) hi = c; else lo = c;
    }
    float m = (lo + hi) * 0.5f;
    #pragma unroll 1
    for (int t = 0; t < 3; ++t) {
        float S = 0.0f, T = 0.0f;
        #pragma unroll
        for (int j = 0; j < EPL; ++j) {
            const float r = sig(xs[j], m);
            S += r;
            T += r * (1.0f - r);
        }
        S = wave_reduce_bcast(S);
        T = wave_reduce_bcast(T);
        const float D  = S * (1.0f / (float)S_DIM) - 0.5f;
        const float Dp = T * (30.0f / (float)S_DIM);
        float step = D * __builtin_amdgcn_rcpf(Dp + 1e-12f);
        step = fminf(0.5f, fmaxf(-0.5f, step));
        m -= step;
    }
    return m;
}

__global__ __launch_bounds__(256)
void dicho_kernel(const float* __restrict__ x, float* __restrict__ out, int bs) {
    __shared__ float band[4][BANDC];     // per-wave private slice, no barriers

    const int wid  = threadIdx.x >> 6;   // 0..3
    const int lane = threadIdx.x & 63;
    const int g    = blockIdx.x * 4 + wid;      // wave id
    const int rowA = g * RPW;
    const int rowB = rowA + 1;
    if (rowA >= bs) return;              // barrier-free -> early return safe
    const bool hasB = (rowB < bs);

    // Issue ALL loads first (A's 8, then B's 8). solve(A) then needs only
    // vmcnt(8) -> runs while B's loads are still in flight.
    const float4* xrA = reinterpret_cast<const float4*>(x + (size_t)rowA * S_DIM);
    const float4* xrB = reinterpret_cast<const float4*>(x + (size_t)(hasB ? rowB : rowA) * S_DIM);
    float4 va[EPL / 4], vb[EPL / 4];
    #pragma unroll
    for (int j = 0; j < EPL / 4; ++j) va[j] = xrA[j * 64 + lane];
    #pragma unroll
    for (int j = 0; j < EPL / 4; ++j) vb[j] = xrB[j * 64 + lane];

    const float mA = solve_row(va, band[wid], lane);
    if (lane == 0) out[rowA] = mA;

    if (hasB) {
        const float mB = solve_row(vb, band[wid], lane);
        if (lane == 0) out[rowB] = mB;
    }
}

extern "C" void kernel_launch(void* const* d_in, const int* in_sizes, int n_in,
                              void* d_out, int out_size, void* d_ws, size_t ws_size,
                              hipStream_t stream) {
    const float* x = (const float*)d_in[0];
    float* out = (float*)d_out;
    const int bs = out_size;                       // 4096 rows, output [bs,1]
    const int waves  = (bs + RPW - 1) / RPW;       // 2048 waves, 2 rows each
    const int blocks = (waves + 3) / 4;            // 4 waves per 256-thr block
    dicho_kernel<<<blocks, 256, 0, stream>>>(x, out, bs);
}